// Round 11
// baseline (296.074 us; speedup 1.0000x reference)
//
#include <hip/hip_runtime.h>

#define NN 50000
#define EE 800000
#define RR 8
#define DD 128
#define SS (NN*RR)        // 400000 segments
#define TE (2*EE)         // 1600000 directed edges
#define NB 782            // dst buckets of 64 nodes
#define NBLK 391          // partition blocks, 4096 directed edges each
#define NS (NB*NBLK)      // 305762 scan elements
#define CONVB 6826        // ceil((NN*DD/4 + 9*DD*DD)/256)
#define SCAN1B 299        // ceil(NS/1024)
#define SCAN3B 1195       // ceil(NS/256)
#define XW_A 131          // xw slice sizes (131+130+130 = 391 blocks)
#define XW_B 130
#define XW_C 130

typedef __attribute__((ext_vector_type(8))) short bf16x8;
typedef __attribute__((ext_vector_type(4))) float f32x4;

// drain all outstanding global_load_lds before a barrier (rule 18; R8 raced)
#define DRAIN_VM do { \
    asm volatile("s_waitcnt vmcnt(0)" ::: "memory"); \
    __builtin_amdgcn_sched_barrier(0); \
  } while (0)

__device__ __forceinline__ unsigned short f2bf(float f){
  unsigned int u = __float_as_uint(f);
  u += 0x7fffu + ((u >> 16) & 1u);   // round-to-nearest-even
  return (unsigned short)(u >> 16);
}
__device__ __forceinline__ float bf_lo(unsigned int w){ return __uint_as_float(w << 16); }
__device__ __forceinline__ float bf_hi(unsigned int w){ return __uint_as_float(w & 0xffff0000u); }

__device__ __forceinline__ void acc8(float* a, uint4 u){
  a[0] += bf_lo(u.x); a[1] += bf_hi(u.x);
  a[2] += bf_lo(u.y); a[3] += bf_hi(u.y);
  a[4] += bf_lo(u.z); a[5] += bf_hi(u.z);
  a[6] += bf_lo(u.w); a[7] += bf_hi(u.w);
}
__device__ __forceinline__ void acc8s(float* a, uint4 u, float s){
  a[0] += s*bf_lo(u.x); a[1] += s*bf_hi(u.x);
  a[2] += s*bf_lo(u.y); a[3] += s*bf_hi(u.y);
  a[4] += s*bf_lo(u.z); a[5] += s*bf_hi(u.z);
  a[6] += s*bf_lo(u.w); a[7] += s*bf_hi(u.w);
}

// directed edge j in [0,TE): j<EE forward (s->d), else reversed
__device__ __forceinline__ void dir_edge(const int* ei, const int* et, int j,
                                         int& s, int& d, int& t){
  if (j < EE){ s = ei[j]; d = ei[EE + j]; t = et[j]; }
  else { int jj = j - EE; s = ei[EE + jj]; d = ei[jj]; t = et[jj]; }
}

// ===========================================================================
// xw block body (shared by 3 fused launches): xw[r] = xb @ W_r, r=0..8.
// 128 rows per block; B panel staged in quarters (32 n-rows = 8 KiB) into a
// 16 KiB double buffer at BsB; explicit vmcnt(0) drain before each barrier.
// ===========================================================================
__device__ __forceinline__ void xw_block(
    int bid, char* BsB,
    const unsigned short* __restrict__ xb,
    const unsigned short* __restrict__ wb,
    unsigned short* __restrict__ xw)
{
  const int tid  = threadIdx.x;
  const int wave = tid >> 6, lane = tid & 63;
  const int l15  = lane & 15, quad = lane >> 4;
  const int row0 = bid * 128 + wave * 32;

  // A fragments: 2 m-tiles x 4 k-slices, loaded once, reused for all 9 rels
  bf16x8 af[2][4];
  #pragma unroll
  for (int m = 0; m < 2; ++m){
    int gr = row0 + m*16 + l15; if (gr >= NN) gr = NN - 1;
    #pragma unroll
    for (int ks = 0; ks < 4; ++ks)
      af[m][ks] = *(const bf16x8*)(xb + (size_t)gr*DD + ks*32 + quad*8);
  }

  // stage quarter (rel rr, quarter qq) into buffer bfb (8 KiB).
  // per wave: 2 calls x (64 lanes x 16 B). Source pre-swizzled (c ^ n&7).
  auto stage = [&](int rr, int qq, int bfb){
    #pragma unroll
    for (int j = 0; j < 2; ++j){
      int rowq = (wave*2 + j)*4 + (lane >> 4);    // 0..31 within quarter
      int n = qq*32 + rowq;
      int c = lane & 15;
      const unsigned short* gp = wb + rr*16384 + n*128 + ((c ^ (n & 7)) << 3);
      __builtin_amdgcn_global_load_lds(
          (const __attribute__((address_space(1))) void*)gp,
          (__attribute__((address_space(3))) void*)(BsB + bfb*8192 + (wave*2 + j)*1024),
          16, 0, 0);
    }
  };

  stage(0, 0, 0);

  #pragma unroll 1
  for (int r = 0; r < 9; ++r){
    unsigned short* xs = xw + (size_t)r * NN * DD;
    #pragma unroll
    for (int q = 0; q < 4; ++q){               // buffer parity q&1 (static)
      DRAIN_VM;                                // own stages landed in LDS
      __syncthreads();                         // -> all waves' stages landed
      {
        int nqq = r*4 + q + 1;
        if (nqq < 36) stage(nqq >> 2, nqq & 3, (q + 1) & 1);
      }
      const char* bb = BsB + (q & 1)*8192;
      #pragma unroll
      for (int lnt = 0; lnt < 2; ++lnt){
        int nt = q*2 + lnt;
        bf16x8 bf4[4];
        #pragma unroll
        for (int ks = 0; ks < 4; ++ks)
          bf4[ks] = *(const bf16x8*)(bb + (lnt*16 + l15)*256
                                        + (((ks*4 + quad) ^ (l15 & 7)) << 4));
        f32x4 C0 = (f32x4)(0.f), C1 = (f32x4)(0.f);
        #pragma unroll
        for (int ks = 0; ks < 4; ++ks){
          C0 = __builtin_amdgcn_mfma_f32_16x16x32_bf16(af[0][ks], bf4[ks], C0, 0, 0, 0);
          C1 = __builtin_amdgcn_mfma_f32_16x16x32_bf16(af[1][ks], bf4[ks], C1, 0, 0, 0);
        }
        #pragma unroll
        for (int i = 0; i < 4; ++i){
          int gr0 = row0 + quad*4 + i;
          int gr1 = row0 + 16 + quad*4 + i;
          if (gr0 < NN) xs[(size_t)gr0*DD + nt*16 + l15] = f2bf(C0[i]);
          if (gr1 < NN) xs[(size_t)gr1*DD + nt*16 + l15] = f2bf(C1[i]);
        }
      }
    }
  }
}

// ===========================================================================
// Launch 1: hist (391 blocks, dst-only loads) || conv (6826 blocks)
// ===========================================================================
__global__ __launch_bounds__(256) void k_histconv(
    const int* __restrict__ ei, const int* __restrict__ et,
    int* __restrict__ hist,
    const float* __restrict__ x, const float* __restrict__ w,
    const float* __restrict__ sw,
    unsigned short* __restrict__ xb, unsigned short* __restrict__ wb)
{
  __shared__ int h[NB];
  if (blockIdx.x < NBLK){
    // ---- per-(bucket,block) histogram — only d is needed ------------------
    int tid = threadIdx.x, bid = blockIdx.x;
    for (int i = tid; i < NB; i += 256) h[i] = 0;
    __syncthreads();
    int j0 = bid*4096;
    for (int k = tid; k < 4096; k += 256){
      int j = j0 + k;
      if (j < TE){
        int d = (j < EE) ? ei[EE + j] : ei[j - EE];
        atomicAdd(&h[d >> 6], 1);           // LDS atomic
      }
    }
    __syncthreads();
    for (int i = tid; i < NB; i += 256) hist[i*NBLK + bid] = h[i];
  } else {
    // ---- conversions ------------------------------------------------------
    int i = (blockIdx.x - NBLK)*256 + threadIdx.x;
    const int M1 = NN*DD/4;            // 1,600,000 float4 groups
    if (i < M1){
      float4 v = ((const float4*)x)[i];
      ushort4 o;
      o.x = f2bf(v.x); o.y = f2bf(v.y); o.z = f2bf(v.z); o.w = f2bf(v.w);
      ((ushort4*)xb)[i] = o;
    } else {
      int j = i - M1;
      if (j < 9*DD*DD){
        int r = j >> 14; int rem = j & 16383; int n = rem >> 7; int k = rem & 127;
        float v = (r < 8) ? w[r*16384 + k*128 + n] : sw[k*128 + n];
        wb[j] = f2bf(v);
      }
    }
  }
}

// ===========================================================================
// Launch 2: scan1 (299 blocks) || xw slice A (131 blocks)
// ===========================================================================
__global__ __launch_bounds__(256, 5) void k_s1xw(
    int* __restrict__ hist, int* __restrict__ blksum,
    const unsigned short* __restrict__ xb,
    const unsigned short* __restrict__ wb,
    unsigned short* __restrict__ xw)
{
  __shared__ __align__(16) char B[16384];
  if (blockIdx.x < SCAN1B){
    int* sd = (int*)B;
    int b = blockIdx.x, tid = threadIdx.x;
    int base = b*1024 + tid*4;
    int v0 = (base+0 < NS) ? hist[base+0] : 0;
    int v1 = (base+1 < NS) ? hist[base+1] : 0;
    int v2 = (base+2 < NS) ? hist[base+2] : 0;
    int v3 = (base+3 < NS) ? hist[base+3] : 0;
    int ts = v0+v1+v2+v3;
    sd[tid] = ts; __syncthreads();
    for (int o = 1; o < 256; o <<= 1){
      int t = (tid >= o) ? sd[tid-o] : 0;
      __syncthreads();
      sd[tid] += t;
      __syncthreads();
    }
    int ex = sd[tid] - ts;
    if (base+0 < NS) hist[base+0] = ex; ex += v0;
    if (base+1 < NS) hist[base+1] = ex; ex += v1;
    if (base+2 < NS) hist[base+2] = ex; ex += v2;
    if (base+3 < NS) hist[base+3] = ex;
    if (tid == 255) blksum[b] = sd[255];   // raw chunk total
  } else {
    xw_block(blockIdx.x - SCAN1B, B, xb, wb, xw);
  }
}

// ===========================================================================
// Launch 3: scan3 (1195 blocks) || xw slice B (130 blocks)
// hist[i] += exclusive-prefix(blksum, i>>10), prefix via in-block reduction.
// ===========================================================================
__global__ __launch_bounds__(256, 5) void k_s3xw(
    int* __restrict__ hist, const int* __restrict__ blksum,
    const unsigned short* __restrict__ xb,
    const unsigned short* __restrict__ wb,
    unsigned short* __restrict__ xw)
{
  __shared__ __align__(16) char B[16384];
  if (blockIdx.x < SCAN3B){
    int* sd = (int*)B;
    int b = blockIdx.x, tid = threadIdx.x;
    int chunk = b >> 2;
    int s = 0;
    if (tid < chunk)       s  = blksum[tid];
    if (tid + 256 < chunk) s += blksum[tid + 256];
    sd[tid] = s; __syncthreads();
    for (int o = 128; o > 0; o >>= 1){
      if (tid < o) sd[tid] += sd[tid + o];
      __syncthreads();
    }
    int i = b*256 + tid;
    if (i < NS) hist[i] += sd[0];
  } else {
    xw_block(blockIdx.x - SCAN3B + XW_A, B, xb, wb, xw);
  }
}

// ===========================================================================
// Launch 4: part (391 blocks) || xw slice C (130 blocks)
// ===========================================================================
__global__ __launch_bounds__(256, 5) void k_partxw(
    const int* __restrict__ ei, const int* __restrict__ et,
    const int* __restrict__ S, unsigned int* __restrict__ P,
    const unsigned short* __restrict__ xb,
    const unsigned short* __restrict__ wb,
    unsigned short* __restrict__ xw)
{
  __shared__ __align__(16) char B[16384];
  if (blockIdx.x < NBLK){
    // ---- partition: place packed edges into bucket slices ----------------
    // packed: src (17b) | dstlo (6b @17) | rel (3b @23)
    int* cur = (int*)B;
    int tid = threadIdx.x, bid = blockIdx.x;
    for (int i = tid; i < NB; i += 256) cur[i] = S[i*NBLK + bid];
    __syncthreads();
    int j0 = bid*4096;
    for (int k = tid; k < 4096; k += 256){
      int j = j0 + k;
      if (j < TE){
        int s, d, t; dir_edge(ei, et, j, s, d, t);
        int b2 = d >> 6;
        int p = atomicAdd(&cur[b2], 1);      // LDS atomic rank
        P[p] = (unsigned int)s | ((unsigned int)(d & 63) << 17)
             | ((unsigned int)t << 23);
      }
    }
  } else {
    xw_block(blockIdx.x - NBLK + XW_A + XW_B, B, xb, wb, xw);
  }
}

// ---- phase B: per-bucket counting sort -> offs + esrc ---------------------
// esrc entries are packed: src (17b) | rel (3b @17)
__global__ __launch_bounds__(256) void k_build(const unsigned int* __restrict__ P,
                                               const int* __restrict__ S,
                                               int* __restrict__ esrc,
                                               int* __restrict__ offs){
  __shared__ int h[512], cu[512], sd[256];
  int tid = threadIdx.x, b = blockIdx.x;
  int pstart = S[b*NBLK];
  int pend   = (b+1 < NB) ? S[(b+1)*NBLK] : TE;
  int ne = pend - pstart;
  h[2*tid] = 0; h[2*tid+1] = 0;
  __syncthreads();
  for (int k = tid; k < ne; k += 256){
    unsigned int u = P[pstart + k];
    int lseg = (int)(((u >> 17) & 63u)*8u + (u >> 23));
    atomicAdd(&h[lseg], 1);                // LDS atomic
  }
  __syncthreads();
  // exclusive scan of 512 bins with 256 threads
  int v0 = h[2*tid], v1 = h[2*tid+1];
  int ts = v0 + v1;
  sd[tid] = ts; __syncthreads();
  for (int o = 1; o < 256; o <<= 1){
    int t = (tid >= o) ? sd[tid-o] : 0;
    __syncthreads();
    sd[tid] += t;
    __syncthreads();
  }
  int ex = sd[tid] - ts;
  cu[2*tid]   = pstart + ex;
  cu[2*tid+1] = pstart + ex + v0;
  int seg0 = b*512;
  if (seg0 + 2*tid     < SS) offs[seg0 + 2*tid]     = cu[2*tid];
  if (seg0 + 2*tid + 1 < SS) offs[seg0 + 2*tid + 1] = cu[2*tid+1];
  if (b == NB-1 && tid == 0) offs[SS] = TE;
  __syncthreads();
  for (int k = tid; k < ne; k += 256){
    unsigned int u = P[pstart + k];
    int lseg = (int)(((u >> 17) & 63u)*8u + (u >> 23));
    int r = atomicAdd(&cu[lseg], 1);       // LDS atomic
    esrc[r] = (int)(u & 0x1ffffu) | (int)(((u >> 23) & 7u) << 17);
  }
}

// ===========================================================================
// k_agg: out[d] = sum_edges (1/deg_seg)*xw[rel][src] + xw[8][d]
// (256,4) = VGPR cap 128 (R9 lesson: never cap below the working set).
// Burst deepened 8 -> 12 (same sequential edge order -> identical result);
// ~88 VGPR est. Latency-limited: 6.5 TB/s delivered at VALUBusy 36%.
// ===========================================================================
__global__ __launch_bounds__(256, 4) void k_agg(
    const unsigned short* __restrict__ xw,
    const int* __restrict__ offs,
    const int* __restrict__ esrc,
    float* __restrict__ out)
{
  const int tid   = threadIdx.x;
  const int lane  = tid & 63;
  const int gl    = lane & 15;
  const int basel = lane & 48;               // group base lane within wave
  const int d     = blockIdx.x * 16 + (tid >> 4);   // NN = 3125*16 exact

  int o = 0;
  if (gl < 9) o = offs[d*8 + gl];
  int onx = __shfl(o, (basel + gl + 1) & 63);       // valid for gl<8
  int cnt = onx - o;
  float scale = (gl < 8 && cnt > 0) ? 1.0f/(float)cnt : 0.0f;
  int ebase = __shfl(o, basel);
  int etot  = __shfl(o, basel + 8) - ebase;

  float a[8] = {0.f,0.f,0.f,0.f,0.f,0.f,0.f,0.f};

  int pk[12];
  #pragma unroll
  for (int s = 0; s < 12; ++s) pk[s] = (s < etot) ? esrc[ebase + s] : 0;

  for (int e = 0; e < etot; e += 12){
    uint4 U[12]; float sc[12];
    #pragma unroll
    for (int s = 0; s < 12; ++s){
      sc[s] = 0.f;
      U[s] = make_uint4(0u,0u,0u,0u);
      if (e + s < etot){
        int rel = (pk[s] >> 17) & 7;
        sc[s]   = __shfl(scale, basel + rel);
        int src = pk[s] & 0x1ffff;
        U[s] = *(const uint4*)(xw + ((size_t)rel*NN + src)*DD + gl*8);
      }
    }
    #pragma unroll
    for (int s = 0; s < 12; ++s){             // prefetch next batch's records
      int en = e + 12 + s;
      pk[s] = (en < etot) ? esrc[ebase + en] : 0;
    }
    #pragma unroll
    for (int s = 0; s < 12; ++s) acc8s(a, U[s], sc[s]);
  }

  // self row (slab 8), scale 1
  {
    uint4 u = *(const uint4*)(xw + ((size_t)8*NN + d)*DD + gl*8);
    acc8(a, u);
  }

  float4 v0; v0.x = a[0]; v0.y = a[1]; v0.z = a[2]; v0.w = a[3];
  float4 v1; v1.x = a[4]; v1.y = a[5]; v1.z = a[6]; v1.w = a[7];
  *(float4*)(out + (size_t)d*DD + gl*8)     = v0;
  *(float4*)(out + (size_t)d*DD + gl*8 + 4) = v1;
}

// ---- memory layout --------------------------------------------------------
// ws:  xb   @ 0          : NN*DD*2 = 12,800,000
//      esrc @ 12,800,000 : TE*4    = 6,400,000
//      offs @ 19,200,000 : (SS+1)*4 -> 1,600,016
//      wb   @ 20,800,016 : 9*DD*DD*2 = 294,912     -> end 21,094,928
//      xw   @ 21,095,168 : 9*NN*DD*2 = 115,200,000 -> end 136,295,168
// out (25.6 MB) doubles as prep scratch, all dead before k_agg writes out:
//      P      @ out+0         : TE*4 = 6,400,000
//      hist   @ out+6,400,000 : NS*4 = 1,223,048
//      blksum @ out+7,623,168 : 1,196
extern "C" void kernel_launch(void* const* d_in, const int* in_sizes, int n_in,
                              void* d_out, int out_size, void* d_ws, size_t ws_size,
                              hipStream_t stream){
  const float* x  = (const float*)d_in[0];
  const float* w  = (const float*)d_in[1];
  const float* sw = (const float*)d_in[2];
  const int*   ei = (const int*)d_in[3];
  const int*   et = (const int*)d_in[4];
  float* out = (float*)d_out;
  char* ws = (char*)d_ws;

  if (ws_size < (size_t)136295168) return;   // big path proven available

  unsigned short* xb = (unsigned short*)(ws + 0);
  int*          esrc = (int*)(ws + 12800000);
  int*          offs = (int*)(ws + 19200000);
  unsigned short* wb = (unsigned short*)(ws + 20800016);
  unsigned short* xw = (unsigned short*)(ws + 21095168);

  unsigned int*    P = (unsigned int*)((char*)d_out + 0);
  int*          hist = (int*)((char*)d_out + 6400000);
  int*        blksum = (int*)((char*)d_out + 7623168);

  k_histconv<<<NBLK + CONVB, 256, 0, stream>>>(ei, et, hist, x, w, sw, xb, wb);
  k_s1xw   <<<SCAN1B + XW_A, 256, 0, stream>>>(hist, blksum, xb, wb, xw);
  k_s3xw   <<<SCAN3B + XW_B, 256, 0, stream>>>(hist, blksum, xb, wb, xw);
  k_partxw <<<NBLK + XW_C, 256, 0, stream>>>(ei, et, hist, P, xb, wb, xw);
  k_build  <<<NB, 256, 0, stream>>>(P, hist, esrc, offs);
  k_agg    <<<NN/16, 256, 0, stream>>>(xw, offs, esrc, out);
}

// Round 12
// 243.769 us; speedup vs baseline: 1.2146x; 1.2146x over previous
//
#include <hip/hip_runtime.h>

#define NN 50000
#define EE 800000
#define RR 8
#define DD 128
#define SS (NN*RR)        // 400000 segments
#define TE (2*EE)         // 1600000 directed edges
#define NB 782            // dst buckets of 64 nodes
#define NBLK 391          // partition blocks, 4096 directed edges each
#define NS (NB*NBLK)      // 305762 scan elements
#define CONVB 6826        // ceil((NN*DD/4 + 9*DD*DD)/256)
#define XWB 391           // ceil(NN/128)

typedef __attribute__((ext_vector_type(8))) short bf16x8;
typedef __attribute__((ext_vector_type(4))) float f32x4;

// drain all outstanding global_load_lds before a barrier (rule 18; R8 raced)
#define DRAIN_VM do { \
    asm volatile("s_waitcnt vmcnt(0)" ::: "memory"); \
    __builtin_amdgcn_sched_barrier(0); \
  } while (0)

__device__ __forceinline__ unsigned short f2bf(float f){
  unsigned int u = __float_as_uint(f);
  u += 0x7fffu + ((u >> 16) & 1u);   // round-to-nearest-even
  return (unsigned short)(u >> 16);
}
__device__ __forceinline__ float bf_lo(unsigned int w){ return __uint_as_float(w << 16); }
__device__ __forceinline__ float bf_hi(unsigned int w){ return __uint_as_float(w & 0xffff0000u); }

__device__ __forceinline__ void acc8(float* a, uint4 u){
  a[0] += bf_lo(u.x); a[1] += bf_hi(u.x);
  a[2] += bf_lo(u.y); a[3] += bf_hi(u.y);
  a[4] += bf_lo(u.z); a[5] += bf_hi(u.z);
  a[6] += bf_lo(u.w); a[7] += bf_hi(u.w);
}
__device__ __forceinline__ void acc8s(float* a, uint4 u, float s){
  a[0] += s*bf_lo(u.x); a[1] += s*bf_hi(u.x);
  a[2] += s*bf_lo(u.y); a[3] += s*bf_hi(u.y);
  a[4] += s*bf_lo(u.z); a[5] += s*bf_hi(u.z);
  a[6] += s*bf_lo(u.w); a[7] += s*bf_hi(u.w);
}

// directed edge j in [0,TE): j<EE forward (s->d), else reversed
__device__ __forceinline__ void dir_edge(const int* ei, const int* et, int j,
                                         int& s, int& d, int& t){
  if (j < EE){ s = ei[j]; d = ei[EE + j]; t = et[j]; }
  else { int jj = j - EE; s = ei[EE + jj]; d = ei[jj]; t = et[jj]; }
}

// ===========================================================================
// Launch 1: hist (391 blocks, dst-only loads) || conv (6826 blocks)
// ===========================================================================
__global__ __launch_bounds__(256) void k_histconv(
    const int* __restrict__ ei, const int* __restrict__ et,
    int* __restrict__ hist,
    const float* __restrict__ x, const float* __restrict__ w,
    const float* __restrict__ sw,
    unsigned short* __restrict__ xb, unsigned short* __restrict__ wb)
{
  __shared__ int h[NB];
  if (blockIdx.x < NBLK){
    // ---- per-(bucket,block) histogram — only d is needed ------------------
    int tid = threadIdx.x, bid = blockIdx.x;
    for (int i = tid; i < NB; i += 256) h[i] = 0;
    __syncthreads();
    int j0 = bid*4096;
    for (int k = tid; k < 4096; k += 256){
      int j = j0 + k;
      if (j < TE){
        int d = (j < EE) ? ei[EE + j] : ei[j - EE];
        atomicAdd(&h[d >> 6], 1);           // LDS atomic
      }
    }
    __syncthreads();
    for (int i = tid; i < NB; i += 256) hist[i*NBLK + bid] = h[i];
  } else {
    // ---- conversions ------------------------------------------------------
    int i = (blockIdx.x - NBLK)*256 + threadIdx.x;
    const int M1 = NN*DD/4;            // 1,600,000 float4 groups
    if (i < M1){
      float4 v = ((const float4*)x)[i];
      ushort4 o;
      o.x = f2bf(v.x); o.y = f2bf(v.y); o.z = f2bf(v.z); o.w = f2bf(v.w);
      ((ushort4*)xb)[i] = o;
    } else {
      int j = i - M1;
      if (j < 9*DD*DD){
        int r = j >> 14; int rem = j & 16383; int n = rem >> 7; int k = rem & 127;
        float v = (r < 8) ? w[r*16384 + k*128 + n] : sw[k*128 + n];
        wb[j] = f2bf(v);
      }
    }
  }
}

// ---- scan over NS elements, 2 kernels (scan2 merged into scan3) -----------
__global__ __launch_bounds__(256) void k_scan1(int* __restrict__ hist,
                                               int* __restrict__ blksum){
  __shared__ int sd[256];
  int b = blockIdx.x, tid = threadIdx.x;
  int base = b*1024 + tid*4;
  int v0 = (base+0 < NS) ? hist[base+0] : 0;
  int v1 = (base+1 < NS) ? hist[base+1] : 0;
  int v2 = (base+2 < NS) ? hist[base+2] : 0;
  int v3 = (base+3 < NS) ? hist[base+3] : 0;
  int ts = v0+v1+v2+v3;
  sd[tid] = ts; __syncthreads();
  for (int o = 1; o < 256; o <<= 1){
    int t = (tid >= o) ? sd[tid-o] : 0;
    __syncthreads();
    sd[tid] += t;
    __syncthreads();
  }
  int ex = sd[tid] - ts;
  if (base+0 < NS) hist[base+0] = ex; ex += v0;
  if (base+1 < NS) hist[base+1] = ex; ex += v1;
  if (base+2 < NS) hist[base+2] = ex; ex += v2;
  if (base+3 < NS) hist[base+3] = ex;
  if (tid == 255) blksum[b] = sd[255];   // raw chunk total (no scan2 pass)
}

// hist[i] += exclusive-prefix(blksum, i>>10) via in-block reduction.
__global__ __launch_bounds__(256) void k_scan3(int* __restrict__ hist,
                                               const int* __restrict__ blksum){
  __shared__ int sd[256];
  int b = blockIdx.x, tid = threadIdx.x;
  int chunk = b >> 2;
  int s = 0;
  if (tid < chunk)       s  = blksum[tid];
  if (tid + 256 < chunk) s += blksum[tid + 256];
  sd[tid] = s; __syncthreads();
  for (int o = 128; o > 0; o >>= 1){
    if (tid < o) sd[tid] += sd[tid + o];
    __syncthreads();
  }
  int i = b*256 + tid;
  if (i < NS) hist[i] += sd[0];
}

// ===========================================================================
// Launch 4: part (391 blocks) || xw (391 blocks).
// xw: B panel staged in quarters (32 n-rows = 8 KiB) into a 3-buffer ring
// (24 KiB) with DEPTH-2 prefetch: at iter t, DRAIN_VM waits on stage(t+1)
// issued a full iteration earlier (latency already elapsed -> cheap drain),
// while stage(t+2) is issued after the barrier. Drain-to-0 semantics kept
// (R9-proven correctness; counted vmcnt is polluted by the C-stores).
// Buffer (t+2)%3 holds quarter t-1, computed before this barrier -> no WAR.
// ===========================================================================
__global__ __launch_bounds__(256, 5) void k_partxw(
    const int* __restrict__ ei, const int* __restrict__ et,
    const int* __restrict__ S, unsigned int* __restrict__ P,
    const unsigned short* __restrict__ xb,
    const unsigned short* __restrict__ wb,
    unsigned short* __restrict__ xw)
{
  __shared__ __align__(16) unsigned short Bs[3][4096];   // 24 KiB union
  if (blockIdx.x < NBLK){
    // ---- partition: place packed edges into bucket slices ----------------
    // packed: src (17b) | dstlo (6b @17) | rel (3b @23)
    int* cur = (int*)&Bs[0][0];
    int tid = threadIdx.x, bid = blockIdx.x;
    for (int i = tid; i < NB; i += 256) cur[i] = S[i*NBLK + bid];
    __syncthreads();
    int j0 = bid*4096;
    for (int k = tid; k < 4096; k += 256){
      int j = j0 + k;
      if (j < TE){
        int s, d, t; dir_edge(ei, et, j, s, d, t);
        int b2 = d >> 6;
        int p = atomicAdd(&cur[b2], 1);      // LDS atomic rank
        P[p] = (unsigned int)s | ((unsigned int)(d & 63) << 17)
             | ((unsigned int)t << 23);
      }
    }
  } else {
    // ---- xw[r] = xb @ W_r, r=0..8; quarter-staged, depth-2 pipeline ------
    const int bid  = blockIdx.x - NBLK;
    const int tid  = threadIdx.x;
    const int wave = tid >> 6, lane = tid & 63;
    const int l15  = lane & 15, quad = lane >> 4;
    const int row0 = bid * 128 + wave * 32;

    // A fragments: 2 m-tiles x 4 k-slices, loaded once, reused for all 9 rels
    bf16x8 af[2][4];
    #pragma unroll
    for (int m = 0; m < 2; ++m){
      int gr = row0 + m*16 + l15; if (gr >= NN) gr = NN - 1;
      #pragma unroll
      for (int ks = 0; ks < 4; ++ks)
        af[m][ks] = *(const bf16x8*)(xb + (size_t)gr*DD + ks*32 + quad*8);
    }

    // stage quarter (rel rr, quarter qq) into ring buffer bfb (8 KiB).
    // per wave: 2 calls x (64 lanes x 16 B). Source pre-swizzled (c ^ n&7).
    auto stage = [&](int rr, int qq, int bfb){
      #pragma unroll
      for (int j = 0; j < 2; ++j){
        int rowq = (wave*2 + j)*4 + (lane >> 4);    // 0..31 within quarter
        int n = qq*32 + rowq;
        int c = lane & 15;
        const unsigned short* gp = wb + rr*16384 + n*128 + ((c ^ (n & 7)) << 3);
        __builtin_amdgcn_global_load_lds(
            (const __attribute__((address_space(1))) void*)gp,
            (__attribute__((address_space(3))) void*)((char*)&Bs[0][0] + bfb*8192 + (wave*2 + j)*1024),
            16, 0, 0);
      }
    };

    stage(0, 0, 0);   // quarter 0 -> buf 0
    stage(0, 1, 1);   // quarter 1 -> buf 1  (depth-2 prologue)

    // 36 quarters; period lcm(3 bufs, 4 quarters/rel) = 12 -> 3 super-iters
    #pragma unroll 1
    for (int sb = 0; sb < 3; ++sb){
      #pragma unroll
      for (int u = 0; u < 12; ++u){            // buf u%3, quarter q=(t&3) static
        DRAIN_VM;                              // stage(t+1) issued last iter: cheap
        __syncthreads();                       // all waves' stage(t) landed
        int t  = sb*12 + u;
        int t2 = t + 2;
        if (t2 < 36) stage(t2 >> 2, t2 & 3, (u + 2) % 3);
        int rel = t >> 2, q = t & 3;
        unsigned short* xs = xw + (size_t)rel * NN * DD;
        const char* bb = (const char*)&Bs[0][0] + (u % 3)*8192;
        #pragma unroll
        for (int lnt = 0; lnt < 2; ++lnt){
          int nt = q*2 + lnt;
          bf16x8 bf4[4];
          #pragma unroll
          for (int ks = 0; ks < 4; ++ks)
            bf4[ks] = *(const bf16x8*)(bb + (lnt*16 + l15)*256
                                          + (((ks*4 + quad) ^ (l15 & 7)) << 4));
          f32x4 C0 = (f32x4)(0.f), C1 = (f32x4)(0.f);
          #pragma unroll
          for (int ks = 0; ks < 4; ++ks){
            C0 = __builtin_amdgcn_mfma_f32_16x16x32_bf16(af[0][ks], bf4[ks], C0, 0, 0, 0);
            C1 = __builtin_amdgcn_mfma_f32_16x16x32_bf16(af[1][ks], bf4[ks], C1, 0, 0, 0);
          }
          #pragma unroll
          for (int i = 0; i < 4; ++i){
            int gr0 = row0 + quad*4 + i;
            int gr1 = row0 + 16 + quad*4 + i;
            if (gr0 < NN) xs[(size_t)gr0*DD + nt*16 + l15] = f2bf(C0[i]);
            if (gr1 < NN) xs[(size_t)gr1*DD + nt*16 + l15] = f2bf(C1[i]);
          }
        }
      }
    }
  }
}

// ---- phase B: per-bucket counting sort -> offs + esrc ---------------------
// esrc entries are packed: src (17b) | rel (3b @17)
__global__ __launch_bounds__(256) void k_build(const unsigned int* __restrict__ P,
                                               const int* __restrict__ S,
                                               int* __restrict__ esrc,
                                               int* __restrict__ offs){
  __shared__ int h[512], cu[512], sd[256];
  int tid = threadIdx.x, b = blockIdx.x;
  int pstart = S[b*NBLK];
  int pend   = (b+1 < NB) ? S[(b+1)*NBLK] : TE;
  int ne = pend - pstart;
  h[2*tid] = 0; h[2*tid+1] = 0;
  __syncthreads();
  for (int k = tid; k < ne; k += 256){
    unsigned int u = P[pstart + k];
    int lseg = (int)(((u >> 17) & 63u)*8u + (u >> 23));
    atomicAdd(&h[lseg], 1);                // LDS atomic
  }
  __syncthreads();
  // exclusive scan of 512 bins with 256 threads
  int v0 = h[2*tid], v1 = h[2*tid+1];
  int ts = v0 + v1;
  sd[tid] = ts; __syncthreads();
  for (int o = 1; o < 256; o <<= 1){
    int t = (tid >= o) ? sd[tid-o] : 0;
    __syncthreads();
    sd[tid] += t;
    __syncthreads();
  }
  int ex = sd[tid] - ts;
  cu[2*tid]   = pstart + ex;
  cu[2*tid+1] = pstart + ex + v0;
  int seg0 = b*512;
  if (seg0 + 2*tid     < SS) offs[seg0 + 2*tid]     = cu[2*tid];
  if (seg0 + 2*tid + 1 < SS) offs[seg0 + 2*tid + 1] = cu[2*tid+1];
  if (b == NB-1 && tid == 0) offs[SS] = TE;
  __syncthreads();
  for (int k = tid; k < ne; k += 256){
    unsigned int u = P[pstart + k];
    int lseg = (int)(((u >> 17) & 63u)*8u + (u >> 23));
    int r = atomicAdd(&cu[lseg], 1);       // LDS atomic
    esrc[r] = (int)(u & 0x1ffffu) | (int)(((u >> 23) & 7u) << 17);
  }
}

// ===========================================================================
// k_agg: out[d] = sum_edges (1/deg_seg)*xw[rel][src] + xw[8][d]
// R10-exact: (256,4), burst 8, VGPR 48, no spills. (R11's burst-12 made the
// compiler hold 64 VGPR and spill 63 MB of scratch — burst 8 is the allocator
// sweet spot.)
// ===========================================================================
__global__ __launch_bounds__(256, 4) void k_agg(
    const unsigned short* __restrict__ xw,
    const int* __restrict__ offs,
    const int* __restrict__ esrc,
    float* __restrict__ out)
{
  const int tid   = threadIdx.x;
  const int lane  = tid & 63;
  const int gl    = lane & 15;
  const int basel = lane & 48;               // group base lane within wave
  const int d     = blockIdx.x * 16 + (tid >> 4);   // NN = 3125*16 exact

  int o = 0;
  if (gl < 9) o = offs[d*8 + gl];
  int onx = __shfl(o, (basel + gl + 1) & 63);       // valid for gl<8
  int cnt = onx - o;
  float scale = (gl < 8 && cnt > 0) ? 1.0f/(float)cnt : 0.0f;
  int ebase = __shfl(o, basel);
  int etot  = __shfl(o, basel + 8) - ebase;

  float a[8] = {0.f,0.f,0.f,0.f,0.f,0.f,0.f,0.f};

  int pk[8];
  #pragma unroll
  for (int s = 0; s < 8; ++s) pk[s] = (s < etot) ? esrc[ebase + s] : 0;

  for (int e = 0; e < etot; e += 8){
    uint4 U[8]; float sc[8];
    #pragma unroll
    for (int s = 0; s < 8; ++s){
      sc[s] = 0.f;
      U[s] = make_uint4(0u,0u,0u,0u);
      if (e + s < etot){
        int rel = (pk[s] >> 17) & 7;
        sc[s]   = __shfl(scale, basel + rel);
        int src = pk[s] & 0x1ffff;
        U[s] = *(const uint4*)(xw + ((size_t)rel*NN + src)*DD + gl*8);
      }
    }
    #pragma unroll
    for (int s = 0; s < 8; ++s){              // prefetch next batch's records
      int en = e + 8 + s;
      pk[s] = (en < etot) ? esrc[ebase + en] : 0;
    }
    #pragma unroll
    for (int s = 0; s < 8; ++s) acc8s(a, U[s], sc[s]);
  }

  // self row (slab 8), scale 1
  {
    uint4 u = *(const uint4*)(xw + ((size_t)8*NN + d)*DD + gl*8);
    acc8(a, u);
  }

  float4 v0; v0.x = a[0]; v0.y = a[1]; v0.z = a[2]; v0.w = a[3];
  float4 v1; v1.x = a[4]; v1.y = a[5]; v1.z = a[6]; v1.w = a[7];
  *(float4*)(out + (size_t)d*DD + gl*8)     = v0;
  *(float4*)(out + (size_t)d*DD + gl*8 + 4) = v1;
}

// ---- memory layout --------------------------------------------------------
// ws:  xb   @ 0          : NN*DD*2 = 12,800,000
//      esrc @ 12,800,000 : TE*4    = 6,400,000
//      offs @ 19,200,000 : (SS+1)*4 -> 1,600,016
//      wb   @ 20,800,016 : 9*DD*DD*2 = 294,912     -> end 21,094,928
//      xw   @ 21,095,168 : 9*NN*DD*2 = 115,200,000 -> end 136,295,168
// out (25.6 MB) doubles as prep scratch, all dead before k_agg writes out:
//      P      @ out+0         : TE*4 = 6,400,000
//      hist   @ out+6,400,000 : NS*4 = 1,223,048
//      blksum @ out+7,623,168 : 1,196
extern "C" void kernel_launch(void* const* d_in, const int* in_sizes, int n_in,
                              void* d_out, int out_size, void* d_ws, size_t ws_size,
                              hipStream_t stream){
  const float* x  = (const float*)d_in[0];
  const float* w  = (const float*)d_in[1];
  const float* sw = (const float*)d_in[2];
  const int*   ei = (const int*)d_in[3];
  const int*   et = (const int*)d_in[4];
  float* out = (float*)d_out;
  char* ws = (char*)d_ws;

  if (ws_size < (size_t)136295168) return;   // big path proven available

  unsigned short* xb = (unsigned short*)(ws + 0);
  int*          esrc = (int*)(ws + 12800000);
  int*          offs = (int*)(ws + 19200000);
  unsigned short* wb = (unsigned short*)(ws + 20800016);
  unsigned short* xw = (unsigned short*)(ws + 21095168);

  unsigned int*    P = (unsigned int*)((char*)d_out + 0);
  int*          hist = (int*)((char*)d_out + 6400000);
  int*        blksum = (int*)((char*)d_out + 7623168);

  k_histconv<<<NBLK + CONVB, 256, 0, stream>>>(ei, et, hist, x, w, sw, xb, wb);
  k_scan1<<<(NS + 1023)/1024, 256, 0, stream>>>(hist, blksum);   // 299 blocks
  k_scan3<<<(NS + 255)/256, 256, 0, stream>>>(hist, blksum);     // 1195 blocks
  k_partxw<<<NBLK + XWB, 256, 0, stream>>>(ei, et, hist, P, xb, wb, xw);
  k_build<<<NB, 256, 0, stream>>>(P, hist, esrc, offs);
  k_agg<<<NN/16, 256, 0, stream>>>(xw, offs, esrc, out);
}

// Round 13
// 228.814 us; speedup vs baseline: 1.2940x; 1.0654x over previous
//
#include <hip/hip_runtime.h>

#define NN 50000
#define EE 800000
#define RR 8
#define DD 128
#define SS (NN*RR)        // 400000 segments
#define TE (2*EE)         // 1600000 directed edges
#define NB 782            // dst buckets of 64 nodes
#define NBLK 391          // partition blocks, 4096 directed edges each
#define NS (NB*NBLK)      // 305762 scan elements
#define CONVB 6826        // ceil((NN*DD/4 + 9*DD*DD)/256)
#define XWB 391           // ceil(NN/128)

typedef __attribute__((ext_vector_type(8))) short bf16x8;
typedef __attribute__((ext_vector_type(4))) float f32x4;

// drain all outstanding global_load_lds before a barrier (rule 18; R8 raced)
#define DRAIN_VM do { \
    asm volatile("s_waitcnt vmcnt(0)" ::: "memory"); \
    __builtin_amdgcn_sched_barrier(0); \
  } while (0)

__device__ __forceinline__ unsigned short f2bf(float f){
  unsigned int u = __float_as_uint(f);
  u += 0x7fffu + ((u >> 16) & 1u);   // round-to-nearest-even
  return (unsigned short)(u >> 16);
}
__device__ __forceinline__ float bf_lo(unsigned int w){ return __uint_as_float(w << 16); }
__device__ __forceinline__ float bf_hi(unsigned int w){ return __uint_as_float(w & 0xffff0000u); }

__device__ __forceinline__ void acc8(float* a, uint4 u){
  a[0] += bf_lo(u.x); a[1] += bf_hi(u.x);
  a[2] += bf_lo(u.y); a[3] += bf_hi(u.y);
  a[4] += bf_lo(u.z); a[5] += bf_hi(u.z);
  a[6] += bf_lo(u.w); a[7] += bf_hi(u.w);
}
__device__ __forceinline__ void acc8s(float* a, uint4 u, float s){
  a[0] += s*bf_lo(u.x); a[1] += s*bf_hi(u.x);
  a[2] += s*bf_lo(u.y); a[3] += s*bf_hi(u.y);
  a[4] += s*bf_lo(u.z); a[5] += s*bf_hi(u.z);
  a[6] += s*bf_lo(u.w); a[7] += s*bf_hi(u.w);
}

// directed edge j in [0,TE): j<EE forward (s->d), else reversed
__device__ __forceinline__ void dir_edge(const int* ei, const int* et, int j,
                                         int& s, int& d, int& t){
  if (j < EE){ s = ei[j]; d = ei[EE + j]; t = et[j]; }
  else { int jj = j - EE; s = ei[EE + jj]; d = ei[jj]; t = et[jj]; }
}

// ===========================================================================
// Launch 1: hist (391 blocks, dst-only loads) || conv (6826 blocks)
// ===========================================================================
__global__ __launch_bounds__(256) void k_histconv(
    const int* __restrict__ ei, const int* __restrict__ et,
    int* __restrict__ hist,
    const float* __restrict__ x, const float* __restrict__ w,
    const float* __restrict__ sw,
    unsigned short* __restrict__ xb, unsigned short* __restrict__ wb)
{
  __shared__ int h[NB];
  if (blockIdx.x < NBLK){
    // ---- per-(bucket,block) histogram — only d is needed ------------------
    int tid = threadIdx.x, bid = blockIdx.x;
    for (int i = tid; i < NB; i += 256) h[i] = 0;
    __syncthreads();
    int j0 = bid*4096;
    for (int k = tid; k < 4096; k += 256){
      int j = j0 + k;
      if (j < TE){
        int d = (j < EE) ? ei[EE + j] : ei[j - EE];
        atomicAdd(&h[d >> 6], 1);           // LDS atomic
      }
    }
    __syncthreads();
    for (int i = tid; i < NB; i += 256) hist[i*NBLK + bid] = h[i];
  } else {
    // ---- conversions ------------------------------------------------------
    int i = (blockIdx.x - NBLK)*256 + threadIdx.x;
    const int M1 = NN*DD/4;            // 1,600,000 float4 groups
    if (i < M1){
      float4 v = ((const float4*)x)[i];
      ushort4 o;
      o.x = f2bf(v.x); o.y = f2bf(v.y); o.z = f2bf(v.z); o.w = f2bf(v.w);
      ((ushort4*)xb)[i] = o;
    } else {
      int j = i - M1;
      if (j < 9*DD*DD){
        int r = j >> 14; int rem = j & 16383; int n = rem >> 7; int k = rem & 127;
        float v = (r < 8) ? w[r*16384 + k*128 + n] : sw[k*128 + n];
        wb[j] = f2bf(v);
      }
    }
  }
}

// ---- scan over NS elements, 2 kernels (scan2 merged into scan3) -----------
__global__ __launch_bounds__(256) void k_scan1(int* __restrict__ hist,
                                               int* __restrict__ blksum){
  __shared__ int sd[256];
  int b = blockIdx.x, tid = threadIdx.x;
  int base = b*1024 + tid*4;
  int v0 = (base+0 < NS) ? hist[base+0] : 0;
  int v1 = (base+1 < NS) ? hist[base+1] : 0;
  int v2 = (base+2 < NS) ? hist[base+2] : 0;
  int v3 = (base+3 < NS) ? hist[base+3] : 0;
  int ts = v0+v1+v2+v3;
  sd[tid] = ts; __syncthreads();
  for (int o = 1; o < 256; o <<= 1){
    int t = (tid >= o) ? sd[tid-o] : 0;
    __syncthreads();
    sd[tid] += t;
    __syncthreads();
  }
  int ex = sd[tid] - ts;
  if (base+0 < NS) hist[base+0] = ex; ex += v0;
  if (base+1 < NS) hist[base+1] = ex; ex += v1;
  if (base+2 < NS) hist[base+2] = ex; ex += v2;
  if (base+3 < NS) hist[base+3] = ex;
  if (tid == 255) blksum[b] = sd[255];   // raw chunk total (no scan2 pass)
}

// hist[i] += exclusive-prefix(blksum, i>>10) via in-block reduction.
__global__ __launch_bounds__(256) void k_scan3(int* __restrict__ hist,
                                               const int* __restrict__ blksum){
  __shared__ int sd[256];
  int b = blockIdx.x, tid = threadIdx.x;
  int chunk = b >> 2;
  int s = 0;
  if (tid < chunk)       s  = blksum[tid];
  if (tid + 256 < chunk) s += blksum[tid + 256];
  sd[tid] = s; __syncthreads();
  for (int o = 128; o > 0; o >>= 1){
    if (tid < o) sd[tid] += sd[tid + o];
    __syncthreads();
  }
  int i = b*256 + tid;
  if (i < NS) hist[i] += sd[0];
}

// ===========================================================================
// Launch 4: part (391 blocks) || xw (391 blocks).
// xw: B panel staged in HALVES (64 n-rows = 16 KiB) into a 2-buffer (32 KiB),
// depth-1 (R9/R10-proven sync: drain-to-0 before every barrier).
// R12 lesson: per-iteration fixed cost (store-retire drain + barrier) is
// ~1.5 us >> compute; halving the iteration count (36 quarters -> 18 halves)
// amortizes it. __launch_bounds__(256,4): 4 blocks/CU at 32 KiB LDS.
// ===========================================================================
__global__ __launch_bounds__(256, 4) void k_partxw(
    const int* __restrict__ ei, const int* __restrict__ et,
    const int* __restrict__ S, unsigned int* __restrict__ P,
    const unsigned short* __restrict__ xb,
    const unsigned short* __restrict__ wb,
    unsigned short* __restrict__ xw)
{
  __shared__ __align__(16) unsigned short Bs[2][8192];   // 32 KiB union
  if (blockIdx.x < NBLK){
    // ---- partition: place packed edges into bucket slices ----------------
    // packed: src (17b) | dstlo (6b @17) | rel (3b @23)
    int* cur = (int*)&Bs[0][0];
    int tid = threadIdx.x, bid = blockIdx.x;
    for (int i = tid; i < NB; i += 256) cur[i] = S[i*NBLK + bid];
    __syncthreads();
    int j0 = bid*4096;
    for (int k = tid; k < 4096; k += 256){
      int j = j0 + k;
      if (j < TE){
        int s, d, t; dir_edge(ei, et, j, s, d, t);
        int b2 = d >> 6;
        int p = atomicAdd(&cur[b2], 1);      // LDS atomic rank
        P[p] = (unsigned int)s | ((unsigned int)(d & 63) << 17)
             | ((unsigned int)t << 23);
      }
    }
  } else {
    // ---- xw[r] = xb @ W_r, r=0..8; half-panel staged, depth-1 ------------
    const int bid  = blockIdx.x - NBLK;
    const int tid  = threadIdx.x;
    const int wave = tid >> 6, lane = tid & 63;
    const int l15  = lane & 15, quad = lane >> 4;
    const int row0 = bid * 128 + wave * 32;

    // A fragments: 2 m-tiles x 4 k-slices, loaded once, reused for all 9 rels
    bf16x8 af[2][4];
    #pragma unroll
    for (int m = 0; m < 2; ++m){
      int gr = row0 + m*16 + l15; if (gr >= NN) gr = NN - 1;
      #pragma unroll
      for (int ks = 0; ks < 4; ++ks)
        af[m][ks] = *(const bf16x8*)(xb + (size_t)gr*DD + ks*32 + quad*8);
    }

    // stage half (rel rr, half hh) into buffer bfb (16 KiB = 64 B-rows).
    // per wave: 4 calls x (64 lanes x 16 B). Source pre-swizzled (c ^ n&7).
    auto stage = [&](int rr, int hh, int bfb){
      #pragma unroll
      for (int j = 0; j < 4; ++j){
        int rowh = wave*16 + j*4 + (lane >> 4);     // 0..63 within half
        int n = hh*64 + rowh;
        int c = lane & 15;
        const unsigned short* gp = wb + rr*16384 + n*128 + ((c ^ (n & 7)) << 3);
        __builtin_amdgcn_global_load_lds(
            (const __attribute__((address_space(1))) void*)gp,
            (__attribute__((address_space(3))) void*)((char*)&Bs[0][0] + bfb*16384 + wave*4096 + j*1024),
            16, 0, 0);
      }
    };

    stage(0, 0, 0);

    #pragma unroll 1
    for (int r = 0; r < 9; ++r){
      unsigned short* xs = xw + (size_t)r * NN * DD;
      #pragma unroll
      for (int u = 0; u < 2; ++u){             // buffer parity u (static)
        DRAIN_VM;                              // own stages landed in LDS
        __syncthreads();                       // -> all waves' stages landed
        int t = r*2 + u;
        if (t + 1 < 18) stage((t + 1) >> 1, (t + 1) & 1, (u + 1) & 1);
        const char* bb = (const char*)&Bs[0][0] + u*16384;
        #pragma unroll
        for (int lnt = 0; lnt < 4; ++lnt){
          int nt = u*4 + lnt;
          bf16x8 bf4[4];
          #pragma unroll
          for (int ks = 0; ks < 4; ++ks)
            bf4[ks] = *(const bf16x8*)(bb + (lnt*16 + l15)*256
                                          + (((ks*4 + quad) ^ (l15 & 7)) << 4));
          f32x4 C0 = (f32x4)(0.f), C1 = (f32x4)(0.f);
          #pragma unroll
          for (int ks = 0; ks < 4; ++ks){
            C0 = __builtin_amdgcn_mfma_f32_16x16x32_bf16(af[0][ks], bf4[ks], C0, 0, 0, 0);
            C1 = __builtin_amdgcn_mfma_f32_16x16x32_bf16(af[1][ks], bf4[ks], C1, 0, 0, 0);
          }
          #pragma unroll
          for (int i = 0; i < 4; ++i){
            int gr0 = row0 + quad*4 + i;
            int gr1 = row0 + 16 + quad*4 + i;
            if (gr0 < NN) xs[(size_t)gr0*DD + nt*16 + l15] = f2bf(C0[i]);
            if (gr1 < NN) xs[(size_t)gr1*DD + nt*16 + l15] = f2bf(C1[i]);
          }
        }
      }
    }
  }
}

// ---- phase B: per-bucket counting sort -> offs + esrc ---------------------
// esrc entries are packed: src (17b) | rel (3b @17)
__global__ __launch_bounds__(256) void k_build(const unsigned int* __restrict__ P,
                                               const int* __restrict__ S,
                                               int* __restrict__ esrc,
                                               int* __restrict__ offs){
  __shared__ int h[512], cu[512], sd[256];
  int tid = threadIdx.x, b = blockIdx.x;
  int pstart = S[b*NBLK];
  int pend   = (b+1 < NB) ? S[(b+1)*NBLK] : TE;
  int ne = pend - pstart;
  h[2*tid] = 0; h[2*tid+1] = 0;
  __syncthreads();
  for (int k = tid; k < ne; k += 256){
    unsigned int u = P[pstart + k];
    int lseg = (int)(((u >> 17) & 63u)*8u + (u >> 23));
    atomicAdd(&h[lseg], 1);                // LDS atomic
  }
  __syncthreads();
  // exclusive scan of 512 bins with 256 threads
  int v0 = h[2*tid], v1 = h[2*tid+1];
  int ts = v0 + v1;
  sd[tid] = ts; __syncthreads();
  for (int o = 1; o < 256; o <<= 1){
    int t = (tid >= o) ? sd[tid-o] : 0;
    __syncthreads();
    sd[tid] += t;
    __syncthreads();
  }
  int ex = sd[tid] - ts;
  cu[2*tid]   = pstart + ex;
  cu[2*tid+1] = pstart + ex + v0;
  int seg0 = b*512;
  if (seg0 + 2*tid     < SS) offs[seg0 + 2*tid]     = cu[2*tid];
  if (seg0 + 2*tid + 1 < SS) offs[seg0 + 2*tid + 1] = cu[2*tid+1];
  if (b == NB-1 && tid == 0) offs[SS] = TE;
  __syncthreads();
  for (int k = tid; k < ne; k += 256){
    unsigned int u = P[pstart + k];
    int lseg = (int)(((u >> 17) & 63u)*8u + (u >> 23));
    int r = atomicAdd(&cu[lseg], 1);       // LDS atomic
    esrc[r] = (int)(u & 0x1ffffu) | (int)(((u >> 23) & 7u) << 17);
  }
}

// ===========================================================================
// k_agg: out[d] = sum_edges (1/deg_seg)*xw[rel][src] + xw[8][d]
// R10-exact: (256,4), burst 8, VGPR 48, no spills. (R11's burst-12 made the
// compiler hold 64 VGPR and spill — burst 8 is the allocator sweet spot.)
// ===========================================================================
__global__ __launch_bounds__(256, 4) void k_agg(
    const unsigned short* __restrict__ xw,
    const int* __restrict__ offs,
    const int* __restrict__ esrc,
    float* __restrict__ out)
{
  const int tid   = threadIdx.x;
  const int lane  = tid & 63;
  const int gl    = lane & 15;
  const int basel = lane & 48;               // group base lane within wave
  const int d     = blockIdx.x * 16 + (tid >> 4);   // NN = 3125*16 exact

  int o = 0;
  if (gl < 9) o = offs[d*8 + gl];
  int onx = __shfl(o, (basel + gl + 1) & 63);       // valid for gl<8
  int cnt = onx - o;
  float scale = (gl < 8 && cnt > 0) ? 1.0f/(float)cnt : 0.0f;
  int ebase = __shfl(o, basel);
  int etot  = __shfl(o, basel + 8) - ebase;

  float a[8] = {0.f,0.f,0.f,0.f,0.f,0.f,0.f,0.f};

  int pk[8];
  #pragma unroll
  for (int s = 0; s < 8; ++s) pk[s] = (s < etot) ? esrc[ebase + s] : 0;

  for (int e = 0; e < etot; e += 8){
    uint4 U[8]; float sc[8];
    #pragma unroll
    for (int s = 0; s < 8; ++s){
      sc[s] = 0.f;
      U[s] = make_uint4(0u,0u,0u,0u);
      if (e + s < etot){
        int rel = (pk[s] >> 17) & 7;
        sc[s]   = __shfl(scale, basel + rel);
        int src = pk[s] & 0x1ffff;
        U[s] = *(const uint4*)(xw + ((size_t)rel*NN + src)*DD + gl*8);
      }
    }
    #pragma unroll
    for (int s = 0; s < 8; ++s){              // prefetch next batch's records
      int en = e + 8 + s;
      pk[s] = (en < etot) ? esrc[ebase + en] : 0;
    }
    #pragma unroll
    for (int s = 0; s < 8; ++s) acc8s(a, U[s], sc[s]);
  }

  // self row (slab 8), scale 1
  {
    uint4 u = *(const uint4*)(xw + ((size_t)8*NN + d)*DD + gl*8);
    acc8(a, u);
  }

  float4 v0; v0.x = a[0]; v0.y = a[1]; v0.z = a[2]; v0.w = a[3];
  float4 v1; v1.x = a[4]; v1.y = a[5]; v1.z = a[6]; v1.w = a[7];
  *(float4*)(out + (size_t)d*DD + gl*8)     = v0;
  *(float4*)(out + (size_t)d*DD + gl*8 + 4) = v1;
}

// ---- memory layout --------------------------------------------------------
// ws:  xb   @ 0          : NN*DD*2 = 12,800,000
//      esrc @ 12,800,000 : TE*4    = 6,400,000
//      offs @ 19,200,000 : (SS+1)*4 -> 1,600,016
//      wb   @ 20,800,016 : 9*DD*DD*2 = 294,912     -> end 21,094,928
//      xw   @ 21,095,168 : 9*NN*DD*2 = 115,200,000 -> end 136,295,168
// out (25.6 MB) doubles as prep scratch, all dead before k_agg writes out:
//      P      @ out+0         : TE*4 = 6,400,000
//      hist   @ out+6,400,000 : NS*4 = 1,223,048
//      blksum @ out+7,623,168 : 1,196
extern "C" void kernel_launch(void* const* d_in, const int* in_sizes, int n_in,
                              void* d_out, int out_size, void* d_ws, size_t ws_size,
                              hipStream_t stream){
  const float* x  = (const float*)d_in[0];
  const float* w  = (const float*)d_in[1];
  const float* sw = (const float*)d_in[2];
  const int*   ei = (const int*)d_in[3];
  const int*   et = (const int*)d_in[4];
  float* out = (float*)d_out;
  char* ws = (char*)d_ws;

  if (ws_size < (size_t)136295168) return;   // big path proven available

  unsigned short* xb = (unsigned short*)(ws + 0);
  int*          esrc = (int*)(ws + 12800000);
  int*          offs = (int*)(ws + 19200000);
  unsigned short* wb = (unsigned short*)(ws + 20800016);
  unsigned short* xw = (unsigned short*)(ws + 21095168);

  unsigned int*    P = (unsigned int*)((char*)d_out + 0);
  int*          hist = (int*)((char*)d_out + 6400000);
  int*        blksum = (int*)((char*)d_out + 7623168);

  k_histconv<<<NBLK + CONVB, 256, 0, stream>>>(ei, et, hist, x, w, sw, xb, wb);
  k_scan1<<<(NS + 1023)/1024, 256, 0, stream>>>(hist, blksum);   // 299 blocks
  k_scan3<<<(NS + 255)/256, 256, 0, stream>>>(hist, blksum);     // 1195 blocks
  k_partxw<<<NBLK + XWB, 256, 0, stream>>>(ei, et, hist, P, xb, wb, xw);
  k_build<<<NB, 256, 0, stream>>>(P, hist, esrc, offs);
  k_agg<<<NN/16, 256, 0, stream>>>(xw, offs, esrc, out);
}